// Round 19
// baseline (430.925 us; speedup 1.0000x reference)
//
#include <hip/hip_runtime.h>
#include <cstdint>
#include <cstddef>

typedef _Float16 f16;
typedef __attribute__((ext_vector_type(8))) _Float16 f16x8;
typedef __attribute__((ext_vector_type(4))) _Float16 f16x4;
typedef __attribute__((ext_vector_type(2))) _Float16 f16x2;
typedef __attribute__((ext_vector_type(4))) float f32x4;

#define MFMA_F16(a, b, c) __builtin_amdgcn_mfma_f32_16x16x32_f16((a), (b), (c), 0, 0, 0)

#define GL2LDS(gsrc, ldst)                                                  \
    __builtin_amdgcn_global_load_lds(                                        \
        (const __attribute__((address_space(1))) void*)(gsrc),               \
        (__attribute__((address_space(3))) void*)(ldst), 16, 0, 0)

#define WAITV(n) asm volatile("s_waitcnt vmcnt(" #n ")" ::: "memory")
#define BAR() __builtin_amdgcn_s_barrier()
#define PRIO(n) __builtin_amdgcn_s_setprio(n)

#define SWZ(row) (((row) >> 1) & 3)

// ws layout (f16 elems): [0,262144) W_L | [262144,524288) W_R |
//   [524288,786432) W_out | xt at elem 1<<20: 8 blade planes [16384][512].
// gp (f16) in d_out: batch b at byte b*16384, blade i at +i*1024, ch n at +2n.
//
// R19: k0/k1 frozen at the 4x-benched optimum (k1 187.3us, MfmaUtil ~32).
// k2 RESTORED to the R2-benched kernel (~122us vs the R8-style ~158us):
// 16 waves, reg-staged A/B with 1-step prefetch, acc[2][8]=64 regs,
// __syncthreads. For k2 the binding resource is stage-latency overlap
// (16-wave TLP), not reads/MFMA -- the R8-k1 model does not transfer.

// ---------------------------------------------------------------------------
// k0: blocks 0..8191 transpose x -> xt f16; blocks 8192..9215 convert weights.
// ---------------------------------------------------------------------------
__global__ __launch_bounds__(256) void k0(const float* __restrict__ x,
                                          const float* __restrict__ wl,
                                          const float* __restrict__ wr,
                                          const float* __restrict__ wo,
                                          f16* __restrict__ wdst,
                                          f16* __restrict__ xt) {
    const int bid = blockIdx.x;
    if (bid >= 8192) {
        int i = (bid - 8192) * 256 + threadIdx.x;
        wdst[i]          = (f16)wl[i];
        wdst[262144 + i] = (f16)wr[i];
        wdst[524288 + i] = (f16)wo[i];
        return;
    }
    const int b = (bid >> 1) * 4 + (threadIdx.x >> 6);
    const int m = (bid & 1) * 256 + (threadIdx.x & 63) * 4;
    const float* src = x + ((size_t)b * 512 + m) * 8;
    f32x4 v[8];
#pragma unroll
    for (int u = 0; u < 8; ++u) v[u] = *(const f32x4*)(src + u * 4);
#pragma unroll
    for (int i = 0; i < 8; ++i) {
        f16x4 w;
#pragma unroll
        for (int j = 0; j < 4; ++j) w[j] = (f16)v[j * 2 + (i >> 2)][i & 3];
        *(f16x4*)(xt + (size_t)i * 8388608 + (size_t)b * 512 + m) = w;
    }
}

// ---------------------------------------------------------------------------
// k1 (R8-benched, 187us, frozen): block 32b x (2 side x 128 ch), 512 thr /
// 8 waves (wb2 x wn4); wave = 16b x 32ch both sides, acc[8][4]. BK=32,
// 3 LDS bufs, 2 phases per K-tile (stageA | stageB), waits 6/4/0.
// ---------------------------------------------------------------------------
__global__ __launch_bounds__(512, 2) void k1(
    const f16* __restrict__ xt, const f16* __restrict__ wf,
    const float* __restrict__ bl_p, const float* __restrict__ br_p,
    char* gp_out)
{
    __shared__ __align__(16) f16 AsF[3 * 8192];   // [buf][blade8][bat32][k32] 48KB
    __shared__ __align__(16) f16 BsF[3 * 8192];   // [buf][side2][ch128][k32]  48KB

    const int L = blockIdx.x;                     // 0..2047, XCD-chunked
    const int xcd = L & 7, sl = L >> 3;
    const int bt = xcd * 64 + (sl >> 2), ct = sl & 3;
    const int b0 = bt * 32, n0 = ct * 128;

    const int tid = threadIdx.x, lane = tid & 63, wv = tid >> 6;  // wv 0..7
    const int wb = wv >> 2, wn = wv & 3;
    const int r_lo = lane & 15, s_hi = lane >> 4;

    const int gA0 = tid, gA1 = tid + 512;
    const int ba0 = gA0 >> 7, ra0 = (gA0 >> 2) & 31, ga0 = (gA0 & 3) ^ SWZ(ra0);
    const int ba1 = gA1 >> 7, ra1 = (gA1 >> 2) & 31, ga1 = (gA1 & 3) ^ SWZ(ra1);
    const f16* aS0 = xt + (size_t)ba0 * 8388608 + (size_t)(b0 + ra0) * 512 + ga0 * 8;
    const f16* aS1 = xt + (size_t)ba1 * 8388608 + (size_t)(b0 + ra1) * 512 + ga1 * 8;
    const int wch = tid >> 2, wg = (tid & 3) ^ SWZ(wch);
    const f16* wS0 = wf + (size_t)(n0 + wch) * 512 + wg * 8;
    const f16* wS1 = wS0 + 262144;

    const int ar = wb * 16 + r_lo;
    const int arow = ar * 32 + ((s_hi ^ SWZ(ar)) << 3);   // + blade*1024
    int bro[4];                                           // L0,L1,R0,R1
#pragma unroll
    for (int t = 0; t < 4; ++t) {
        const int nrow = ((t & 2) ? 128 : 0) + wn * 32 + (t & 1) * 16 + r_lo;
        bro[t] = nrow * 32 + ((s_hi ^ SWZ(nrow)) << 3);
    }

    f32x4 acc[8][4];
    const f32x4 zero = {0.f, 0.f, 0.f, 0.f};
#pragma unroll
    for (int i = 0; i < 8; ++i)
#pragma unroll
        for (int t = 0; t < 4; ++t) acc[i][t] = zero;

    auto stageA = [&](int kt, int buf) {
        GL2LDS(aS0 + kt * 32, AsF + buf * 8192 + wv * 512);
        GL2LDS(aS1 + kt * 32, AsF + buf * 8192 + 4096 + wv * 512);
    };
    auto stageB = [&](int kt, int buf) {
        GL2LDS(wS0 + kt * 32, BsF + buf * 8192 + wv * 512);
        GL2LDS(wS1 + kt * 32, BsF + buf * 8192 + 4096 + wv * 512);
    };

    stageA(0, 0); stageB(0, 0);
    stageA(1, 1); stageB(1, 1);

#pragma unroll
    for (int kt = 0; kt < 16; ++kt) {
        const int buf = kt % 3, nbuf = (kt + 2) % 3;
        const f16* Ab = AsF + buf * 8192;
        const f16* Bb = BsF + buf * 8192;
        // ---------- phase 0 ----------
        if (kt < 14) stageA(kt + 2, nbuf);
        if (kt <= 13)      { WAITV(6); }
        else if (kt == 14) { WAITV(4); }
        else               { WAITV(0); }
        BAR();
        f16x8 bf[4];
#pragma unroll
        for (int t = 0; t < 4; ++t) bf[t] = *(const f16x8*)(Bb + bro[t]);
        {
            f16x8 a0 = *(const f16x8*)(Ab + 0 * 1024 + arow);
            f16x8 a1 = *(const f16x8*)(Ab + 1 * 1024 + arow);
            f16x8 a2 = *(const f16x8*)(Ab + 2 * 1024 + arow);
            f16x8 a3 = *(const f16x8*)(Ab + 3 * 1024 + arow);
            PRIO(1);
#pragma unroll
            for (int t = 0; t < 4; ++t) {
                acc[0][t] = MFMA_F16(a0, bf[t], acc[0][t]);
                acc[1][t] = MFMA_F16(a1, bf[t], acc[1][t]);
                acc[2][t] = MFMA_F16(a2, bf[t], acc[2][t]);
                acc[3][t] = MFMA_F16(a3, bf[t], acc[3][t]);
            }
            PRIO(0);
        }
        BAR();
        // ---------- phase 1 ----------
        if (kt < 14) stageB(kt + 2, nbuf);
        {
            f16x8 a4 = *(const f16x8*)(Ab + 4 * 1024 + arow);
            f16x8 a5 = *(const f16x8*)(Ab + 5 * 1024 + arow);
            f16x8 a6 = *(const f16x8*)(Ab + 6 * 1024 + arow);
            f16x8 a7 = *(const f16x8*)(Ab + 7 * 1024 + arow);
            PRIO(1);
#pragma unroll
            for (int t = 0; t < 4; ++t) {
                acc[4][t] = MFMA_F16(a4, bf[t], acc[4][t]);
                acc[5][t] = MFMA_F16(a5, bf[t], acc[5][t]);
                acc[6][t] = MFMA_F16(a6, bf[t], acc[6][t]);
                acc[7][t] = MFMA_F16(a7, bf[t], acc[7][t]);
            }
            PRIO(0);
        }
        BAR();
    }

    // epilogue: bias + Cl(3,0) geometric product -> gp f16 in d_out
#pragma unroll
    for (int t = 0; t < 2; ++t) {
        const int ch = n0 + wn * 32 + t * 16 + r_lo;
        const float blv = bl_p[ch], brv = br_p[ch];
#pragma unroll
        for (int rr = 0; rr < 4; ++rr) {
            const int b_g = b0 + wb * 16 + s_hi * 4 + rr;
            float Lv[8], Rv[8];
#pragma unroll
            for (int i = 0; i < 8; ++i) { Lv[i] = acc[i][t][rr]; Rv[i] = acc[i][2 + t][rr]; }
            Lv[0] += blv; Rv[0] += brv;
            float g[8];
            g[0] = Lv[0]*Rv[0]+Lv[1]*Rv[1]+Lv[2]*Rv[2]+Lv[3]*Rv[3]-Lv[4]*Rv[4]-Lv[5]*Rv[5]-Lv[6]*Rv[6]-Lv[7]*Rv[7];
            g[1] = Lv[0]*Rv[1]+Lv[1]*Rv[0]-Lv[2]*Rv[4]-Lv[3]*Rv[5]+Lv[4]*Rv[2]+Lv[5]*Rv[3]-Lv[6]*Rv[7]-Lv[7]*Rv[6];
            g[2] = Lv[0]*Rv[2]+Lv[1]*Rv[4]+Lv[2]*Rv[0]-Lv[3]*Rv[6]-Lv[4]*Rv[1]+Lv[5]*Rv[7]+Lv[6]*Rv[3]+Lv[7]*Rv[5];
            g[3] = Lv[0]*Rv[3]+Lv[1]*Rv[5]+Lv[2]*Rv[6]+Lv[3]*Rv[0]-Lv[4]*Rv[7]-Lv[5]*Rv[1]-Lv[6]*Rv[2]-Lv[7]*Rv[4];
            g[4] = Lv[0]*Rv[4]+Lv[1]*Rv[2]-Lv[2]*Rv[1]+Lv[3]*Rv[7]+Lv[4]*Rv[0]-Lv[5]*Rv[6]+Lv[6]*Rv[5]+Lv[7]*Rv[3];
            g[5] = Lv[0]*Rv[5]+Lv[1]*Rv[3]-Lv[2]*Rv[7]-Lv[3]*Rv[1]+Lv[4]*Rv[6]+Lv[5]*Rv[0]-Lv[6]*Rv[4]-Lv[7]*Rv[2];
            g[6] = Lv[0]*Rv[6]+Lv[1]*Rv[7]+Lv[2]*Rv[3]-Lv[3]*Rv[2]-Lv[4]*Rv[5]+Lv[5]*Rv[4]+Lv[6]*Rv[0]+Lv[7]*Rv[1];
            g[7] = Lv[0]*Rv[7]+Lv[1]*Rv[6]-Lv[2]*Rv[5]+Lv[3]*Rv[4]+Lv[4]*Rv[3]-Lv[5]*Rv[2]+Lv[6]*Rv[1]+Lv[7]*Rv[0];
            char* dst = gp_out + (size_t)b_g * 16384 + (size_t)ch * 2;
#pragma unroll
            for (int i = 0; i < 8; ++i) *(f16*)(dst + (size_t)i * 1024) = (f16)g[i];
        }
    }
}

// ---------------------------------------------------------------------------
// k2 (R2-benched, ~122us): out = gp @ W_out^T + bias, MVLayerNorm, scale.
// Block 16 batches x ALL 512 channels, 1024 thr / 16 waves (2 ch strips
// each, acc[2][8]), K=512, dbuf LDS, reg-staged with 1-step prefetch.
// Reads gp f16 from its own batch regions of d_out, overwrites fp32 only
// after the K-loop (post-barrier) -> no hazard. Restored verbatim.
// ---------------------------------------------------------------------------
__global__ __launch_bounds__(1024, 4) void k2(
    const char* gp_in, const f16* __restrict__ wo,
    const float* __restrict__ bo_p, const float* __restrict__ an_p,
    float* outp)
{
    __shared__ __align__(16) f16 As[2][8][16*32];   // 16KB
    __shared__ __align__(16) f16 Bs[2][512*32];     // 64KB
    __shared__ float red[16][16];                   // [batch][wave]

    const int b0   = blockIdx.x * 16;
    const int tid  = threadIdx.x;
    const int lane = tid & 63;
    const int wv   = tid >> 6;            // 0..15
    const int r_lo = lane & 15, s_hi = lane >> 4;

    f32x4 acc[2][8];
    const f32x4 zero = {0.f, 0.f, 0.f, 0.f};
#pragma unroll
    for (int st = 0; st < 2; ++st)
#pragma unroll
        for (int i = 0; i < 8; ++i) acc[st][i] = zero;

    // staging maps
    const int ablade = tid >> 6, arow = (tid >> 2) & 15, ac = tid & 3;  // tid<512
    const char* asrc0 = gp_in + (size_t)(b0 + arow) * 16384 + (size_t)(ablade & 7) * 1024 + ac * 16;
    const int aw = arow * 32 + ((ac ^ (arow & 3)) << 3);
    const int brow = tid >> 1, bc2 = (tid & 1) * 2;
    const f16* bsrc0 = wo + (size_t)brow * 512 + bc2 * 8;
    const int bw0 = brow * 32 + (((bc2    ) ^ (brow & 3)) << 3);
    const int bw1 = brow * 32 + (((bc2 + 1) ^ (brow & 3)) << 3);

    auto stage = [&](int kk, int buf) {
        if (tid < 512) {
            f16x8 v = *(const f16x8*)(asrc0 + (size_t)kk * 64);
            *(f16x8*)&As[buf][ablade][aw] = v;
        }
        const f16* bs = bsrc0 + kk * 32;
        f16x8 v0 = *(const f16x8*)(bs);
        f16x8 v1 = *(const f16x8*)(bs + 8);
        *(f16x8*)&Bs[buf][bw0] = v0;
        *(f16x8*)&Bs[buf][bw1] = v1;
    };

    const int nl0 = wv * 32 + r_lo, nl1 = nl0 + 16;
    const int boff0 = nl0 * 32 + ((s_hi ^ (nl0 & 3)) << 3);
    const int boff1 = nl1 * 32 + ((s_hi ^ (nl1 & 3)) << 3);
    const int aoff  = r_lo * 32 + ((s_hi ^ (r_lo & 3)) << 3);

    stage(0, 0);
    for (int kk = 0; kk < 16; ++kk) {
        __syncthreads();
        if (kk < 15) stage(kk + 1, (kk + 1) & 1);
        const int buf = kk & 1;
        f16x8 bf0 = *(const f16x8*)&Bs[buf][boff0];
        f16x8 bf1 = *(const f16x8*)&Bs[buf][boff1];
#pragma unroll
        for (int i = 0; i < 8; ++i) {
            f16x8 a = *(const f16x8*)&As[buf][i][aoff];
            acc[0][i] = MFMA_F16(a, bf0, acc[0][i]);
            acc[1][i] = MFMA_F16(a, bf1, acc[1][i]);
        }
    }

    const float bo0 = bo_p[nl0], bo1 = bo_p[nl1];
    const float an0 = an_p[nl0], an1 = an_p[nl1];

    // per-(batch,channel) multivector norms, summed over this lane's channels
    float partial[4];
#pragma unroll
    for (int rr = 0; rr < 4; ++rr) {
        float o = acc[0][0][rr] + bo0;
        float ss = o * o;
#pragma unroll
        for (int i = 1; i < 8; ++i) ss += acc[0][i][rr] * acc[0][i][rr];
        float s = sqrtf(ss);
        o = acc[1][0][rr] + bo1;
        ss = o * o;
#pragma unroll
        for (int i = 1; i < 8; ++i) ss += acc[1][i][rr] * acc[1][i][rr];
        partial[rr] = s + sqrtf(ss);
    }
#pragma unroll
    for (int off = 1; off < 16; off <<= 1) {
#pragma unroll
        for (int rr = 0; rr < 4; ++rr) partial[rr] += __shfl_xor(partial[rr], off);
    }
    if (r_lo == 0) {
#pragma unroll
        for (int rr = 0; rr < 4; ++rr) red[s_hi * 4 + rr][wv] = partial[rr];
    }
    __syncthreads();   // also guarantees all gp reads done before fp32 stores

#pragma unroll
    for (int rr = 0; rr < 4; ++rr) {
        float tot = 0.f;
#pragma unroll
        for (int w = 0; w < 16; ++w) tot += red[s_hi * 4 + rr][w];
        const float inv = 1.0f / (tot * (1.0f / 512.0f) + 1e-6f);
        const float sc0 = an0 * inv, sc1 = an1 * inv;
        const int b_g = b0 + s_hi * 4 + rr;
        float* dst = outp + (size_t)b_g * 4096;
        f32x4 v;
        v[0] = (acc[0][0][rr] + bo0) * sc0;
        v[1] = acc[0][1][rr] * sc0;
        v[2] = acc[0][2][rr] * sc0;
        v[3] = acc[0][3][rr] * sc0;
        *(f32x4*)(dst + (size_t)nl0 * 8) = v;
        v[0] = acc[0][4][rr] * sc0;
        v[1] = acc[0][5][rr] * sc0;
        v[2] = acc[0][6][rr] * sc0;
        v[3] = acc[0][7][rr] * sc0;
        *(f32x4*)(dst + (size_t)nl0 * 8 + 4) = v;
        v[0] = (acc[1][0][rr] + bo1) * sc1;
        v[1] = acc[1][1][rr] * sc1;
        v[2] = acc[1][2][rr] * sc1;
        v[3] = acc[1][3][rr] * sc1;
        *(f32x4*)(dst + (size_t)nl1 * 8) = v;
        v[0] = acc[1][4][rr] * sc1;
        v[1] = acc[1][5][rr] * sc1;
        v[2] = acc[1][6][rr] * sc1;
        v[3] = acc[1][7][rr] * sc1;
        *(f32x4*)(dst + (size_t)nl1 * 8 + 4) = v;
    }
}

// ---------------------------------------------------------------------------
extern "C" void kernel_launch(void* const* d_in, const int* in_sizes, int n_in,
                              void* d_out, int out_size, void* d_ws, size_t ws_size,
                              hipStream_t stream) {
    const float* x  = (const float*)d_in[0];
    const float* wl = (const float*)d_in[1];
    const float* bl = (const float*)d_in[2];
    const float* wr = (const float*)d_in[3];
    const float* br = (const float*)d_in[4];
    const float* wo = (const float*)d_in[5];
    const float* bo = (const float*)d_in[6];
    const float* an = (const float*)d_in[7];
    f16* wf = (f16*)d_ws;
    f16* xt = wf + (1 << 20);   // byte offset 2MB

    hipLaunchKernelGGL(k0, dim3(9216), dim3(256), 0, stream, x, wl, wr, wo, wf, xt);
    hipLaunchKernelGGL(k1, dim3(2048), dim3(512), 0, stream, xt, wf, bl, br, (char*)d_out);
    hipLaunchKernelGGL(k2, dim3(1024), dim3(1024), 0, stream,
                       (const char*)d_out, wf + 524288, bo, an, (float*)d_out);
}

// Round 20
// 407.692 us; speedup vs baseline: 1.0570x; 1.0570x over previous
//
#include <hip/hip_runtime.h>
#include <cstdint>
#include <cstddef>

typedef _Float16 f16;
typedef __attribute__((ext_vector_type(8))) _Float16 f16x8;
typedef __attribute__((ext_vector_type(4))) _Float16 f16x4;
typedef __attribute__((ext_vector_type(4))) float f32x4;

#define MFMA_F16(a, b, c) __builtin_amdgcn_mfma_f32_16x16x32_f16((a), (b), (c), 0, 0, 0)

#define GL2LDS(gsrc, ldst)                                                  \
    __builtin_amdgcn_global_load_lds(                                        \
        (const __attribute__((address_space(1))) void*)(gsrc),               \
        (__attribute__((address_space(3))) void*)(ldst), 16, 0, 0)

#define WAITV(n) asm volatile("s_waitcnt vmcnt(" #n ")" ::: "memory")
#define BAR() __builtin_amdgcn_s_barrier()
#define PRIO(n) __builtin_amdgcn_s_setprio(n)

#define SWZ(row) (((row) >> 1) & 3)

// ws layout (f16 elems): [0,262144) W_L | [262144,524288) W_R |
//   [524288,786432) W_out | xt at elem 1<<20: 8 blade planes [16384][512].
// gp (f16) in d_out: batch b at byte b*16384, blade i at +i*1024, ch n at +2n.
//
// FINAL CONVERGED CONFIG (benched 407.6 R14 / 412.5 R16 / 412.9 R18).
// k1: 187.3us x4 reproductions, MfmaUtil ~32 — the validated structural
// ceiling of the blade-fused GP (every wave reads 8 A-planes; 256-reg/lane
// cap => ch<=32 => 0.375 ds_read_b128/MFMA). k2: R8 2-phase (~158us), beat
// R2-style reg-staged (177us, A/B'd R19) and 5 other variants. All escape
// paths measured and closed: occupancy up (-20%), B-direct (neutral),
// tile up (spills, 6x), barrier rate halved (neutral), FIFO reorder
// (neutral), fp8 (error budget), flag-fusion (4x), bank conflicts (0).

// ---------------------------------------------------------------------------
// k0: blocks 0..8191 transpose x -> xt f16; blocks 8192..9215 convert weights.
// (HBM-bound: ~66us for 384MB moved.)
// ---------------------------------------------------------------------------
__global__ __launch_bounds__(256) void k0(const float* __restrict__ x,
                                          const float* __restrict__ wl,
                                          const float* __restrict__ wr,
                                          const float* __restrict__ wo,
                                          f16* __restrict__ wdst,
                                          f16* __restrict__ xt) {
    const int bid = blockIdx.x;
    if (bid >= 8192) {
        int i = (bid - 8192) * 256 + threadIdx.x;
        wdst[i]          = (f16)wl[i];
        wdst[262144 + i] = (f16)wr[i];
        wdst[524288 + i] = (f16)wo[i];
        return;
    }
    const int b = (bid >> 1) * 4 + (threadIdx.x >> 6);
    const int m = (bid & 1) * 256 + (threadIdx.x & 63) * 4;
    const float* src = x + ((size_t)b * 512 + m) * 8;
    f32x4 v[8];
#pragma unroll
    for (int u = 0; u < 8; ++u) v[u] = *(const f32x4*)(src + u * 4);
#pragma unroll
    for (int i = 0; i < 8; ++i) {
        f16x4 w;
#pragma unroll
        for (int j = 0; j < 4; ++j) w[j] = (f16)v[j * 2 + (i >> 2)][i & 3];
        *(f16x4*)(xt + (size_t)i * 8388608 + (size_t)b * 512 + m) = w;
    }
}

// ---------------------------------------------------------------------------
// k1 (R8-benched, 187us): block 32b x (2 side x 128 ch), 512 thr / 8 waves
// (wb2 x wn4); wave = 16b x 32ch both sides, acc[8][4]. BK=32, 3 LDS bufs,
// 2 phases per K-tile (stageA | stageB), waits 6/4/0.
// ---------------------------------------------------------------------------
__global__ __launch_bounds__(512, 2) void k1(
    const f16* __restrict__ xt, const f16* __restrict__ wf,
    const float* __restrict__ bl_p, const float* __restrict__ br_p,
    char* gp_out)
{
    __shared__ __align__(16) f16 AsF[3 * 8192];   // [buf][blade8][bat32][k32] 48KB
    __shared__ __align__(16) f16 BsF[3 * 8192];   // [buf][side2][ch128][k32]  48KB

    const int L = blockIdx.x;                     // 0..2047, XCD-chunked
    const int xcd = L & 7, sl = L >> 3;
    const int bt = xcd * 64 + (sl >> 2), ct = sl & 3;
    const int b0 = bt * 32, n0 = ct * 128;

    const int tid = threadIdx.x, lane = tid & 63, wv = tid >> 6;  // wv 0..7
    const int wb = wv >> 2, wn = wv & 3;
    const int r_lo = lane & 15, s_hi = lane >> 4;

    // A staging sources (2 calls x 512 lanes; swizzle keyed on bat)
    const int gA0 = tid, gA1 = tid + 512;
    const int ba0 = gA0 >> 7, ra0 = (gA0 >> 2) & 31, ga0 = (gA0 & 3) ^ SWZ(ra0);
    const int ba1 = gA1 >> 7, ra1 = (gA1 >> 2) & 31, ga1 = (gA1 & 3) ^ SWZ(ra1);
    const f16* aS0 = xt + (size_t)ba0 * 8388608 + (size_t)(b0 + ra0) * 512 + ga0 * 8;
    const f16* aS1 = xt + (size_t)ba1 * 8388608 + (size_t)(b0 + ra1) * 512 + ga1 * 8;
    // B staging sources (2 calls = side L / side R; swizzle keyed on ch)
    const int wch = tid >> 2, wg = (tid & 3) ^ SWZ(wch);
    const f16* wS0 = wf + (size_t)(n0 + wch) * 512 + wg * 8;
    const f16* wS1 = wS0 + 262144;

    // compute-side offsets
    const int ar = wb * 16 + r_lo;
    const int arow = ar * 32 + ((s_hi ^ SWZ(ar)) << 3);   // + blade*1024
    int bro[4];                                           // L0,L1,R0,R1
#pragma unroll
    for (int t = 0; t < 4; ++t) {
        const int nrow = ((t & 2) ? 128 : 0) + wn * 32 + (t & 1) * 16 + r_lo;
        bro[t] = nrow * 32 + ((s_hi ^ SWZ(nrow)) << 3);
    }

    f32x4 acc[8][4];
    const f32x4 zero = {0.f, 0.f, 0.f, 0.f};
#pragma unroll
    for (int i = 0; i < 8; ++i)
#pragma unroll
        for (int t = 0; t < 4; ++t) acc[i][t] = zero;

    auto stageA = [&](int kt, int buf) {
        GL2LDS(aS0 + kt * 32, AsF + buf * 8192 + wv * 512);
        GL2LDS(aS1 + kt * 32, AsF + buf * 8192 + 4096 + wv * 512);
    };
    auto stageB = [&](int kt, int buf) {
        GL2LDS(wS0 + kt * 32, BsF + buf * 8192 + wv * 512);
        GL2LDS(wS1 + kt * 32, BsF + buf * 8192 + 4096 + wv * 512);
    };

    stageA(0, 0); stageB(0, 0);
    stageA(1, 1); stageB(1, 1);

#pragma unroll
    for (int kt = 0; kt < 16; ++kt) {
        const int buf = kt % 3, nbuf = (kt + 2) % 3;
        const f16* Ab = AsF + buf * 8192;
        const f16* Bb = BsF + buf * 8192;
        // ---------- phase 0 ----------
        if (kt < 14) stageA(kt + 2, nbuf);
        if (kt <= 13)      { WAITV(6); }
        else if (kt == 14) { WAITV(4); }
        else               { WAITV(0); }
        BAR();
        f16x8 bf[4];
#pragma unroll
        for (int t = 0; t < 4; ++t) bf[t] = *(const f16x8*)(Bb + bro[t]);
        {
            f16x8 a0 = *(const f16x8*)(Ab + 0 * 1024 + arow);
            f16x8 a1 = *(const f16x8*)(Ab + 1 * 1024 + arow);
            f16x8 a2 = *(const f16x8*)(Ab + 2 * 1024 + arow);
            f16x8 a3 = *(const f16x8*)(Ab + 3 * 1024 + arow);
            PRIO(1);
#pragma unroll
            for (int t = 0; t < 4; ++t) {
                acc[0][t] = MFMA_F16(a0, bf[t], acc[0][t]);
                acc[1][t] = MFMA_F16(a1, bf[t], acc[1][t]);
                acc[2][t] = MFMA_F16(a2, bf[t], acc[2][t]);
                acc[3][t] = MFMA_F16(a3, bf[t], acc[3][t]);
            }
            PRIO(0);
        }
        BAR();
        // ---------- phase 1 ----------
        if (kt < 14) stageB(kt + 2, nbuf);
        {
            f16x8 a4 = *(const f16x8*)(Ab + 4 * 1024 + arow);
            f16x8 a5 = *(const f16x8*)(Ab + 5 * 1024 + arow);
            f16x8 a6 = *(const f16x8*)(Ab + 6 * 1024 + arow);
            f16x8 a7 = *(const f16x8*)(Ab + 7 * 1024 + arow);
            PRIO(1);
#pragma unroll
            for (int t = 0; t < 4; ++t) {
                acc[4][t] = MFMA_F16(a4, bf[t], acc[4][t]);
                acc[5][t] = MFMA_F16(a5, bf[t], acc[5][t]);
                acc[6][t] = MFMA_F16(a6, bf[t], acc[6][t]);
                acc[7][t] = MFMA_F16(a7, bf[t], acc[7][t]);
            }
            PRIO(0);
        }
        BAR();
    }

    // epilogue: bias + Cl(3,0) geometric product -> gp f16 in d_out
#pragma unroll
    for (int t = 0; t < 2; ++t) {
        const int ch = n0 + wn * 32 + t * 16 + r_lo;
        const float blv = bl_p[ch], brv = br_p[ch];
#pragma unroll
        for (int rr = 0; rr < 4; ++rr) {
            const int b_g = b0 + wb * 16 + s_hi * 4 + rr;
            float Lv[8], Rv[8];
#pragma unroll
            for (int i = 0; i < 8; ++i) { Lv[i] = acc[i][t][rr]; Rv[i] = acc[i][2 + t][rr]; }
            Lv[0] += blv; Rv[0] += brv;
            float g[8];
            g[0] = Lv[0]*Rv[0]+Lv[1]*Rv[1]+Lv[2]*Rv[2]+Lv[3]*Rv[3]-Lv[4]*Rv[4]-Lv[5]*Rv[5]-Lv[6]*Rv[6]-Lv[7]*Rv[7];
            g[1] = Lv[0]*Rv[1]+Lv[1]*Rv[0]-Lv[2]*Rv[4]-Lv[3]*Rv[5]+Lv[4]*Rv[2]+Lv[5]*Rv[3]-Lv[6]*Rv[7]-Lv[7]*Rv[6];
            g[2] = Lv[0]*Rv[2]+Lv[1]*Rv[4]+Lv[2]*Rv[0]-Lv[3]*Rv[6]-Lv[4]*Rv[1]+Lv[5]*Rv[7]+Lv[6]*Rv[3]+Lv[7]*Rv[5];
            g[3] = Lv[0]*Rv[3]+Lv[1]*Rv[5]+Lv[2]*Rv[6]+Lv[3]*Rv[0]-Lv[4]*Rv[7]-Lv[5]*Rv[1]-Lv[6]*Rv[2]-Lv[7]*Rv[4];
            g[4] = Lv[0]*Rv[4]+Lv[1]*Rv[2]-Lv[2]*Rv[1]+Lv[3]*Rv[7]+Lv[4]*Rv[0]-Lv[5]*Rv[6]+Lv[6]*Rv[5]+Lv[7]*Rv[3];
            g[5] = Lv[0]*Rv[5]+Lv[1]*Rv[3]-Lv[2]*Rv[7]-Lv[3]*Rv[1]+Lv[4]*Rv[6]+Lv[5]*Rv[0]-Lv[6]*Rv[4]-Lv[7]*Rv[2];
            g[6] = Lv[0]*Rv[6]+Lv[1]*Rv[7]+Lv[2]*Rv[3]-Lv[3]*Rv[2]-Lv[4]*Rv[5]+Lv[5]*Rv[4]+Lv[6]*Rv[0]+Lv[7]*Rv[1];
            g[7] = Lv[0]*Rv[7]+Lv[1]*Rv[6]-Lv[2]*Rv[5]+Lv[3]*Rv[4]+Lv[4]*Rv[3]-Lv[5]*Rv[2]+Lv[6]*Rv[1]+Lv[7]*Rv[0];
            char* dst = gp_out + (size_t)b_g * 16384 + (size_t)ch * 2;
#pragma unroll
            for (int i = 0; i < 8; ++i) *(f16*)(dst + (size_t)i * 1024) = (f16)g[i];
        }
    }
}

// ---------------------------------------------------------------------------
// k2 (R8-benched): block 16b x 512ch (norm intra-block), 512 thr / 8 waves,
// wave = 16b x 64ch (acc[8][4]); gp from d_out, 3 bufs, 2-phase, waits 7/5/0.
// Reads gp only from its own batch regions; overwrites them fp32 after.
// ---------------------------------------------------------------------------
__global__ __launch_bounds__(512, 2) void k2(
    const char* gp_in, const f16* __restrict__ wo,
    const float* __restrict__ bo_p, const float* __restrict__ an_p,
    float* outp)
{
    __shared__ __align__(16) f16 AsF[3 * 4096];
    __shared__ __align__(16) f16 BsF[3 * 16384];
    __shared__ float red[16][8];

    const int b0 = blockIdx.x * 16;
    const int tid = threadIdx.x, lane = tid & 63, wv = tid >> 6;
    const int r_lo = lane & 15, s_hi = lane >> 4;

    const int abl = tid >> 6, arw = (tid >> 2) & 15, agp = (tid & 3) ^ SWZ(arw);
    const char* aS = gp_in + (size_t)(b0 + arw) * 16384 + (size_t)abl * 1024 + agp * 16;
    const f16* bS[4];
#pragma unroll
    for (int j = 0; j < 4; ++j) {
        const int n = j * 128 + (tid >> 2);
        bS[j] = wo + (size_t)n * 512 + ((tid & 3) ^ SWZ(n)) * 8;
    }

    const int aoff = r_lo * 32 + ((s_hi ^ SWZ(r_lo)) << 3);
    int bro[4];
#pragma unroll
    for (int t = 0; t < 4; ++t) {
        const int nrow = wv * 64 + t * 16 + r_lo;
        bro[t] = nrow * 32 + ((s_hi ^ SWZ(nrow)) << 3);
    }

    f32x4 acc[8][4];
    const f32x4 zero = {0.f, 0.f, 0.f, 0.f};
#pragma unroll
    for (int i = 0; i < 8; ++i)
#pragma unroll
        for (int t = 0; t < 4; ++t) acc[i][t] = zero;

    auto stageB01 = [&](int kt, int buf) {
        GL2LDS(bS[0] + kt * 32, BsF + buf * 16384 + 0 * 4096 + wv * 512);
        GL2LDS(bS[1] + kt * 32, BsF + buf * 16384 + 1 * 4096 + wv * 512);
    };
    auto stageAB23 = [&](int kt, int buf) {
        GL2LDS(aS + kt * 64, AsF + buf * 4096 + wv * 512);
        GL2LDS(bS[2] + kt * 32, BsF + buf * 16384 + 2 * 4096 + wv * 512);
        GL2LDS(bS[3] + kt * 32, BsF + buf * 16384 + 3 * 4096 + wv * 512);
    };

    stageB01(0, 0); stageAB23(0, 0);
    stageB01(1, 1); stageAB23(1, 1);

#pragma unroll
    for (int kt = 0; kt < 16; ++kt) {
        const int buf = kt % 3, nbuf = (kt + 2) % 3;
        const f16* Ab = AsF + buf * 4096;
        const f16* Bb = BsF + buf * 16384;
        if (kt < 14) stageB01(kt + 2, nbuf);
        if (kt <= 13)      { WAITV(7); }
        else if (kt == 14) { WAITV(5); }
        else               { WAITV(0); }
        BAR();
        f16x8 af[8];
#pragma unroll
        for (int i = 0; i < 8; ++i) af[i] = *(const f16x8*)(Ab + i * 512 + aoff);
        {
            f16x8 b0f = *(const f16x8*)(Bb + bro[0]);
            f16x8 b1f = *(const f16x8*)(Bb + bro[1]);
            PRIO(1);
#pragma unroll
            for (int i = 0; i < 8; ++i) {
                acc[i][0] = MFMA_F16(af[i], b0f, acc[i][0]);
                acc[i][1] = MFMA_F16(af[i], b1f, acc[i][1]);
            }
            PRIO(0);
        }
        BAR();
        if (kt < 14) stageAB23(kt + 2, nbuf);
        {
            f16x8 b2f = *(const f16x8*)(Bb + bro[2]);
            f16x8 b3f = *(const f16x8*)(Bb + bro[3]);
            PRIO(1);
#pragma unroll
            for (int i = 0; i < 8; ++i) {
                acc[i][2] = MFMA_F16(af[i], b2f, acc[i][2]);
                acc[i][3] = MFMA_F16(af[i], b3f, acc[i][3]);
            }
            PRIO(0);
        }
        BAR();
    }

    float bo_t[4], an_t[4];
#pragma unroll
    for (int t = 0; t < 4; ++t) {
        const int c = wv * 64 + t * 16 + r_lo;
        bo_t[t] = bo_p[c]; an_t[t] = an_p[c];
    }

    float partial[4];
#pragma unroll
    for (int rr = 0; rr < 4; ++rr) {
        float sum = 0.f;
#pragma unroll
        for (int t = 0; t < 4; ++t) {
            float o = acc[0][t][rr] + bo_t[t];
            float ss = o * o;
#pragma unroll
            for (int i = 1; i < 8; ++i) ss += acc[i][t][rr] * acc[i][t][rr];
            sum += sqrtf(ss);
        }
        partial[rr] = sum;
    }
#pragma unroll
    for (int off = 1; off < 16; off <<= 1)
#pragma unroll
        for (int rr = 0; rr < 4; ++rr) partial[rr] += __shfl_xor(partial[rr], off);
    if (r_lo == 0)
#pragma unroll
        for (int rr = 0; rr < 4; ++rr) red[s_hi * 4 + rr][wv] = partial[rr];
    __syncthreads();

#pragma unroll
    for (int rr = 0; rr < 4; ++rr) {
        float tot = 0.f;
#pragma unroll
        for (int w = 0; w < 8; ++w) tot += red[s_hi * 4 + rr][w];
        const float inv = 1.0f / (tot * (1.0f / 512.0f) + 1e-6f);
        const int b_g = b0 + s_hi * 4 + rr;
        float* dst = outp + (size_t)b_g * 4096;
#pragma unroll
        for (int t = 0; t < 4; ++t) {
            const float sc = an_t[t] * inv;
            const int c = wv * 64 + t * 16 + r_lo;
            f32x4 v0, v1;
            v0[0] = (acc[0][t][rr] + bo_t[t]) * sc;
            v0[1] = acc[1][t][rr] * sc; v0[2] = acc[2][t][rr] * sc; v0[3] = acc[3][t][rr] * sc;
            v1[0] = acc[4][t][rr] * sc; v1[1] = acc[5][t][rr] * sc;
            v1[2] = acc[6][t][rr] * sc; v1[3] = acc[7][t][rr] * sc;
            *(f32x4*)(dst + (size_t)c * 8) = v0;
            *(f32x4*)(dst + (size_t)c * 8 + 4) = v1;
        }
    }
}

// ---------------------------------------------------------------------------
extern "C" void kernel_launch(void* const* d_in, const int* in_sizes, int n_in,
                              void* d_out, int out_size, void* d_ws, size_t ws_size,
                              hipStream_t stream) {
    const float* x  = (const float*)d_in[0];
    const float* wl = (const float*)d_in[1];
    const float* bl = (const float*)d_in[2];
    const float* wr = (const float*)d_in[3];
    const float* br = (const float*)d_in[4];
    const float* wo = (const float*)d_in[5];
    const float* bo = (const float*)d_in[6];
    const float* an = (const float*)d_in[7];
    f16* wf = (f16*)d_ws;
    f16* xt = wf + (1 << 20);   // byte offset 2MB

    hipLaunchKernelGGL(k0, dim3(9216), dim3(256), 0, stream, x, wl, wr, wo, wf, xt);
    hipLaunchKernelGGL(k1, dim3(2048), dim3(512), 0, stream, xt, wf, bl, br, (char*)d_out);
    hipLaunchKernelGGL(k2, dim3(1024), dim3(512), 0, stream,
                       (const char*)d_out, wf + 524288, bo, an, (float*)d_out);
}